// Round 1
// 1077.658 us; speedup vs baseline: 1.0067x; 1.0067x over previous
//
#include <hip/hip_runtime.h>
#include <math.h>

// ---------------------------------------------------------------------------
// StageA_GNN: full pipeline
//   enc GEMM -> mlp2 -> gate projections -> [CSR build] -> L x (agg -> upd MLP
//   + LN) -> U=softplus(h@toU) -> mu = exp(clip(log lib + log(U@W^T) + alpha
//   + bcorr))
// All fp32. CSR by dst built per call (no atomics in hot loops).
// ---------------------------------------------------------------------------

static __device__ __forceinline__ float sigmoidf_fast(float x){
  return __builtin_amdgcn_rcpf(1.f + __expf(-x));
}
static __device__ __forceinline__ float softplusf_dev(float x){
  return (x > 20.f) ? x : log1pf(__expf(x));
}

// ---------------- prep kernels ----------------
__global__ void k_prep_node(const float* __restrict__ rho_raw, const float* __restrict__ lib,
                            float* __restrict__ rho, float* __restrict__ loglib, int N){
  int i = blockIdx.x*256 + threadIdx.x;
  if (i < N){
    rho[i]    = sigmoidf_fast(rho_raw[i]);
    loglib[i] = __logf(fmaxf(lib[i], 1e-8f));
  }
}

__global__ void k_prep_W(const float* __restrict__ W_raw, float* __restrict__ WT, int C, int K){
  int i = blockIdx.x*256 + threadIdx.x;
  if (i < C*K){
    int k = i / C, c = i - k*C;
    WT[i] = softplusf_dev(W_raw[c*K + k]);   // WT[k][c] = softplus(W[c][k])
  }
}

__global__ void k_prep_bcorr(const float* __restrict__ P, const float* __restrict__ Q,
                             float* __restrict__ bcorr, int S, int R, int C){
  __shared__ float pm[64];
  int t = threadIdx.x;
  if (t < R){
    float s = 0.f;
    for (int i = 0; i < S; ++i) s += P[i*R + t];
    pm[t] = s / (float)S;
  }
  __syncthreads();
  for (int c = t; c < C; c += 256){
    for (int s8 = 0; s8 < S; ++s8){
      float a = 0.f;
      for (int r = 0; r < R; ++r) a += (P[s8*R + r] - pm[r]) * Q[c*R + r];
      bcorr[s8*C + c] = a;
    }
  }
}

// ---------------- CSR build ----------------
__global__ void k_hist(const int* __restrict__ dst, int* __restrict__ cnt, int E){
  int i = blockIdx.x*256 + threadIdx.x;
  if (i < E) atomicAdd(&cnt[dst[i]], 1);
}

__global__ void k_scan1(const int* __restrict__ cnt, int* __restrict__ offs,
                        int* __restrict__ blksum, int N){
  __shared__ int s[1024];
  int t = threadIdx.x;
  int i = blockIdx.x*1024 + t;
  int v = (i < N) ? cnt[i] : 0;
  s[t] = v;
  __syncthreads();
  for (int off = 1; off < 1024; off <<= 1){
    int a = (t >= off) ? s[t-off] : 0;
    __syncthreads();
    s[t] += a;
    __syncthreads();
  }
  if (i < N) offs[i] = s[t] - v;          // block-local exclusive
  if (t == 1023) blksum[blockIdx.x] = s[t];
}

__global__ void k_scan2(int* __restrict__ blksum, int nblk){
  if (threadIdx.x == 0 && blockIdx.x == 0){
    int run = 0;
    for (int i = 0; i < nblk; ++i){ int t = blksum[i]; blksum[i] = run; run += t; }
  }
}

__global__ void k_scan3(int* __restrict__ offs, const int* __restrict__ blksum, int N, int E){
  int i = blockIdx.x*256 + threadIdx.x;
  if (i < N) offs[i] += blksum[i >> 10];
  else if (i == N) offs[N] = E;
}

__global__ void k_fill(const int* __restrict__ src, const int* __restrict__ dst,
                       const float* __restrict__ base_w, const float* __restrict__ dist,
                       const float* __restrict__ rho,
                       const int* __restrict__ offs, int* __restrict__ fill,
                       float4* __restrict__ csr4, int E){
  int i = blockIdx.x*256 + threadIdx.x;
  if (i < E){
    int d = dst[i];
    int p = offs[d] + atomicAdd(&fill[d], 1);
    int s = src[i];
    csr4[p] = make_float4(__int_as_float(s), dist[i], base_w[i]*rho[s], 0.f);
  }
}

// ---------------- encoder layer 1: h1 = relu(X @ W1 + b1) ----------------
// X: (N,C) fp32, W1: (C,64). 128 rows/block, BK=40, 256 threads.
// Per-thread 8 rows x 4 cols. Xs stored TRANSPOSED [k][row ^ swz] so the
// x-fragment is a single ds_read_b128 (3 LDS instrs per 32 FMAs, was 5 per 16).
// Global->reg prefetch of tile t+1 issued before compute of tile t (T14).
__global__ __launch_bounds__(256) void k_enc1(const float* __restrict__ X,
                                              const float* __restrict__ W1,
                                              const float* __restrict__ b1,
                                              float* __restrict__ h1, int N, int C){
  __shared__ float Xs[40*128];   // [k][row ^ ((k>>2)&7)<<2]
  __shared__ float Ws[40*68];    // [k][col], pad 68
  int tid = threadIdx.x;
  int row0 = blockIdx.x*128;
  int tx4 = (tid & 15)*4;        // col base
  int ty8 = (tid >> 4)*8;        // row base

  // X loader: 1280 float4 slots, q = tid + i*256; row = q/10, kq = q%10
  int xlds[5];
  bool okX[5];
  const float* xg[5];
  #pragma unroll
  for (int i = 0; i < 5; ++i){
    int q = tid + i*256;
    int r = q/10, kq = q - r*10;
    okX[i] = (row0 + r) < N;
    xg[i] = X + (size_t)(okX[i] ? (row0 + r) : 0)*C + kq*4;
    xlds[i] = kq*4*128 + (r ^ ((kq & 7) << 2));
  }
  // W loader: 640 float4 slots; kk = q>>4, c4 = q&15
  int wkk[3], wc4[3];
  #pragma unroll
  for (int i = 0; i < 3; ++i){
    int q = tid + i*256;
    wkk[i] = q >> 4; wc4[i] = (q & 15)*4;
  }
  bool wok2 = (tid < 128);       // slot i==2 valid iff tid+512 < 640

  float4 xr[5], wr[3];
  float acc[8][4];
  #pragma unroll
  for (int p = 0; p < 8; ++p){
    acc[p][0]=0.f; acc[p][1]=0.f; acc[p][2]=0.f; acc[p][3]=0.f;
  }

  auto loadTile = [&](int k0){
    #pragma unroll
    for (int i = 0; i < 5; ++i)
      xr[i] = okX[i] ? *(const float4*)(xg[i] + k0) : make_float4(0.f,0.f,0.f,0.f);
    const float* wp = W1 + (size_t)k0*64;
    #pragma unroll
    for (int i = 0; i < 3; ++i)
      if (i < 2 || wok2) wr[i] = *(const float4*)(wp + wkk[i]*64 + wc4[i]);
  };
  auto storeLDS = [&](){
    #pragma unroll
    for (int i = 0; i < 5; ++i){
      int b = xlds[i];
      Xs[b      ] = xr[i].x;
      Xs[b + 128] = xr[i].y;
      Xs[b + 256] = xr[i].z;
      Xs[b + 384] = xr[i].w;
    }
    #pragma unroll
    for (int i = 0; i < 3; ++i)
      if (i < 2 || wok2) *(float4*)(Ws + wkk[i]*68 + wc4[i]) = wr[i];
  };

  loadTile(0);
  storeLDS();
  __syncthreads();

  int nt = C/40;                 // C=1000 -> 25 tiles
  for (int t = 0; t < nt; ++t){
    if (t+1 < nt) loadTile((t+1)*40);   // prefetch hides under FMA phase
    #pragma unroll 8
    for (int k = 0; k < 40; ++k){
      int s = ((k>>2)&7)<<2;
      const float* xp = Xs + k*128;
      float4 xa = *(const float4*)(xp + (ty8 ^ s));
      float4 xb = *(const float4*)(xp + ((ty8+4) ^ s));
      float4 wv = *(const float4*)(Ws + k*68 + tx4);
      float xv[8] = {xa.x,xa.y,xa.z,xa.w,xb.x,xb.y,xb.z,xb.w};
      #pragma unroll
      for (int p = 0; p < 8; ++p){
        acc[p][0] = fmaf(xv[p], wv.x, acc[p][0]);
        acc[p][1] = fmaf(xv[p], wv.y, acc[p][1]);
        acc[p][2] = fmaf(xv[p], wv.z, acc[p][2]);
        acc[p][3] = fmaf(xv[p], wv.w, acc[p][3]);
      }
    }
    __syncthreads();
    if (t+1 < nt){ storeLDS(); __syncthreads(); }
  }

  float4 bv = *(const float4*)(b1 + tx4);
  #pragma unroll
  for (int p = 0; p < 8; ++p){
    int row = row0 + ty8 + p;
    if (row < N){
      float4 o;
      o.x = fmaxf(acc[p][0] + bv.x, 0.f);
      o.y = fmaxf(acc[p][1] + bv.y, 0.f);
      o.z = fmaxf(acc[p][2] + bv.z, 0.f);
      o.w = fmaxf(acc[p][3] + bv.w, 0.f);
      *(float4*)(h1 + (size_t)row*64 + tx4) = o;
    }
  }
}

// ---------------- small GEMM: Y = epi(X(N,64) @ W(64,CO) + bias) ----------
// EPI: 0=none 1=relu 2=layernorm(residual HP) 3=softplus
template<int CO, int EPI>
__global__ __launch_bounds__(256) void k_small_gemm(
    const float* __restrict__ X, int xstride, int xoff,
    const float* __restrict__ W, const float* __restrict__ bias,
    float* __restrict__ Y, int ystride, int yoff,
    const float* __restrict__ HP, int hpstride, int hpoff,
    const float* __restrict__ lng, const float* __restrict__ lnb,
    int nrows){
  constexpr int CPT = CO/16;
  __shared__ float Xs[64*68];
  __shared__ float Ws[64*CO];
  int tid = threadIdx.x;
  int row0 = blockIdx.x*64;
  for (int q = tid; q < 1024; q += 256){
    int r = q >> 4, kq = q & 15;
    int row = row0 + r;
    float4 v = make_float4(0.f,0.f,0.f,0.f);
    if (row < nrows) v = *(const float4*)(X + (size_t)row*xstride + xoff + kq*4);
    *(float4*)(Xs + r*68 + kq*4) = v;
  }
  for (int i = tid; i < 64*CO; i += 256) Ws[i] = W[i];
  __syncthreads();
  int tx = tid & 15, ty = tid >> 4;
  int colbase = tx*CPT;
  float acc[4][CPT];
  #pragma unroll
  for (int p = 0; p < 4; ++p)
    #pragma unroll
    for (int c = 0; c < CPT; ++c) acc[p][c] = 0.f;
  #pragma unroll 8
  for (int k = 0; k < 64; ++k){
    float wv[CPT];
    if constexpr (CPT == 4){
      float4 t = *(const float4*)(Ws + k*CO + colbase);
      wv[0]=t.x; wv[1]=t.y; wv[2]=t.z; wv[3]=t.w;
    } else {
      float2 t = *(const float2*)(Ws + k*CO + colbase);
      wv[0]=t.x; wv[1]=t.y;
    }
    #pragma unroll
    for (int p = 0; p < 4; ++p){
      float x = Xs[(ty*4 + p)*68 + k];
      #pragma unroll
      for (int c = 0; c < CPT; ++c) acc[p][c] = fmaf(x, wv[c], acc[p][c]);
    }
  }
  float bv[CPT];
  #pragma unroll
  for (int c = 0; c < CPT; ++c) bv[c] = bias ? bias[colbase + c] : 0.f;

  if constexpr (EPI == 2){
    // layernorm(h + u)*g + b ; CO must be 64
    float lg[4], lb[4];
    #pragma unroll
    for (int c = 0; c < 4; ++c){ lg[c] = lng[colbase + c]; lb[c] = lnb[colbase + c]; }
    float hn[4][4];
    #pragma unroll
    for (int p = 0; p < 4; ++p){
      int row = row0 + ty*4 + p;
      #pragma unroll
      for (int c = 0; c < 4; ++c){
        float h = (row < nrows) ? HP[(size_t)row*hpstride + hpoff + colbase + c] : 0.f;
        hn[p][c] = h + acc[p][c] + bv[c];
      }
    }
    float rs[4], vs[4];
    #pragma unroll
    for (int p = 0; p < 4; ++p) rs[p] = hn[p][0]+hn[p][1]+hn[p][2]+hn[p][3];
    #pragma unroll
    for (int m = 8; m >= 1; m >>= 1)
      #pragma unroll
      for (int p = 0; p < 4; ++p) rs[p] += __shfl_xor(rs[p], m, 64);
    float mean[4], inv[4];
    #pragma unroll
    for (int p = 0; p < 4; ++p) mean[p] = rs[p] * 0.015625f;
    #pragma unroll
    for (int p = 0; p < 4; ++p){
      float d0 = hn[p][0]-mean[p], d1 = hn[p][1]-mean[p];
      float d2 = hn[p][2]-mean[p], d3 = hn[p][3]-mean[p];
      vs[p] = d0*d0 + d1*d1 + d2*d2 + d3*d3;
    }
    #pragma unroll
    for (int m = 8; m >= 1; m >>= 1)
      #pragma unroll
      for (int p = 0; p < 4; ++p) vs[p] += __shfl_xor(vs[p], m, 64);
    #pragma unroll
    for (int p = 0; p < 4; ++p) inv[p] = 1.f / sqrtf(vs[p]*0.015625f + 1e-5f);
    #pragma unroll
    for (int p = 0; p < 4; ++p){
      int row = row0 + ty*4 + p;
      if (row < nrows){
        float o0 = fmaf(lg[0], (hn[p][0]-mean[p])*inv[p], lb[0]);
        float o1 = fmaf(lg[1], (hn[p][1]-mean[p])*inv[p], lb[1]);
        float o2 = fmaf(lg[2], (hn[p][2]-mean[p])*inv[p], lb[2]);
        float o3 = fmaf(lg[3], (hn[p][3]-mean[p])*inv[p], lb[3]);
        *(float4*)(Y + (size_t)row*ystride + yoff + colbase) = make_float4(o0,o1,o2,o3);
      }
    }
  } else {
    #pragma unroll
    for (int p = 0; p < 4; ++p){
      int row = row0 + ty*4 + p;
      if (row < nrows){
        float o[CPT];
        #pragma unroll
        for (int c = 0; c < CPT; ++c){
          float v = acc[p][c] + bv[c];
          if constexpr (EPI == 1) v = fmaxf(v, 0.f);
          if constexpr (EPI == 3) v = softplusf_dev(v);
          o[c] = v;
        }
        if constexpr (CPT == 4)
          *(float4*)(Y + (size_t)row*ystride + yoff + colbase) = make_float4(o[0],o[1],o[2],o[3]);
        else
          *(float2*)(Y + (size_t)row*ystride + yoff + colbase) = make_float2(o[0],o[1]);
      }
    }
  }
}

// ---------------- aggregation: neigh = (sum_e w*h[src]) / (sum_e w + eps) --
// wave per node; lane = channel. pk row: [a(64) | h(64)].
__global__ __launch_bounds__(256) void k_agg(
    const float* __restrict__ pk, const float* __restrict__ bbuf,
    const float* __restrict__ rho, const float4* __restrict__ csr4,
    const int* __restrict__ offs,
    const float* __restrict__ gw1, const float* __restrict__ gb1,
    const float* __restrict__ gw2, const float* __restrict__ gb2,
    float* __restrict__ neigh, int N){
  int tid = threadIdx.x;
  int j = tid & 63;
  int v = blockIdx.x*4 + (tid >> 6);
  if (v >= N) return;
  float gcj  = gw1[128*64 + j];      // dist row of gate_w1
  float gw2j = gw2[j];
  float bb   = bbuf[(size_t)v*64 + j] + gb1[j];
  float gb2v = gb2[0];
  float rhov = rho[v];
  int beg = offs[v], end = offs[v+1];
  float acc = 0.f, deg = 0.f;
  for (int i = beg; i < end; ++i){
    float4 e = csr4[i];
    int s = __float_as_int(e.x);
    const float* ps = pk + (size_t)s*128;
    float av = ps[j];
    float hv = ps[64 + j];
    float t = fmaxf(fmaf(e.y, gcj, av + bb), 0.f) * gw2j;
    t += __shfl_xor(t, 32, 64);
    t += __shfl_xor(t, 16, 64);
    t += __shfl_xor(t,  8, 64);
    t += __shfl_xor(t,  4, 64);
    t += __shfl_xor(t,  2, 64);
    t += __shfl_xor(t,  1, 64);
    float gate = sigmoidf_fast(t + gb2v);
    float wgt = gate * e.z * rhov;   // e.z = base_w*rho[src]
    acc = fmaf(wgt, hv, acc);
    deg += wgt;
  }
  neigh[(size_t)v*64 + j] = acc * __builtin_amdgcn_rcpf(deg + 1e-8f);
}

// ---------------- final: mu = exp(clip(loglib + log(U@W^T) + alpha + bcorr))
__global__ __launch_bounds__(256) void k_final(
    const float* __restrict__ U, const float* __restrict__ WT,
    const float* __restrict__ alpha, const float* __restrict__ bcorr,
    const float* __restrict__ loglib, const int* __restrict__ sid,
    float* __restrict__ out, int N, int C, int npb){
  int c = blockIdx.x*256 + threadIdx.x;
  bool active = (c < C);
  int cc = active ? c : (C-1);
  float wreg[32];
  #pragma unroll
  for (int k = 0; k < 32; ++k) wreg[k] = WT[k*C + cc];
  float al = alpha[cc];
  int n0 = blockIdx.y * npb;
  int n1 = min(n0 + npb, N);
  for (int n = n0; n < n1; ++n){
    int sd   = sid[n];        // wave-uniform -> scalar loads
    float ll = loglib[n];
    const float* Ur = U + (size_t)n*32;
    float dot = 0.f;
    #pragma unroll
    for (int k = 0; k < 32; ++k) dot = fmaf(Ur[k], wreg[k], dot);
    float lm = ll + __logf(fmaxf(dot, 1e-8f)) + al + bcorr[sd*C + cc];
    lm = fminf(fmaxf(lm, -20.f), 20.f);
    if (active) out[(size_t)n*C + c] = __expf(lm);
  }
}

// ---------------------------------------------------------------------------
extern "C" void kernel_launch(void* const* d_in, const int* in_sizes, int n_in,
                              void* d_out, int out_size, void* d_ws, size_t ws_size,
                              hipStream_t stream){
  const float* x_common = (const float*)d_in[0];
  const int*   src      = (const int*)  d_in[1];
  const int*   dst      = (const int*)  d_in[2];
  const float* base_w   = (const float*)d_in[3];
  const float* dist     = (const float*)d_in[4];
  const float* lib      = (const float*)d_in[5];
  const int*   sid      = (const int*)  d_in[6];
  const float* enc_w1   = (const float*)d_in[7];
  const float* enc_b1   = (const float*)d_in[8];
  const float* enc_w2   = (const float*)d_in[9];
  const float* enc_b2   = (const float*)d_in[10];
  const float* upd_w1   = (const float*)d_in[11];
  const float* upd_b1   = (const float*)d_in[12];
  const float* upd_w2   = (const float*)d_in[13];
  const float* upd_b2   = (const float*)d_in[14];
  const float* ln_g     = (const float*)d_in[15];
  const float* ln_b     = (const float*)d_in[16];
  const float* gate_w1  = (const float*)d_in[17];
  const float* gate_b1  = (const float*)d_in[18];
  const float* gate_w2  = (const float*)d_in[19];
  const float* gate_b2  = (const float*)d_in[20];
  const float* rho_raw  = (const float*)d_in[21];
  const float* toU_w    = (const float*)d_in[22];
  const float* toU_b    = (const float*)d_in[23];
  const float* W_raw    = (const float*)d_in[24];
  const float* alpha    = (const float*)d_in[25];
  const float* P        = (const float*)d_in[26];
  const float* Q        = (const float*)d_in[27];

  const int N = in_sizes[5];            // 50000
  const int E = in_sizes[1];            // 800000
  const int C = in_sizes[25];           // 1000
  const int K = in_sizes[23];           // 32
  const int R = in_sizes[27] / C;       // 16
  const int S = in_sizes[26] / R;       // 8
  const int L = in_sizes[15] / 64;      // 2

  float* w = (float*)d_ws;
  size_t o = 0;
  auto alloc = [&](size_t n)->float*{ float* p = w + o; o += (n + 63) & ~((size_t)63); return p; };
  float*  pkA   = alloc((size_t)N*128);   // [a | h] packed per node
  float*  pkB   = alloc((size_t)N*128);
  float*  bbuf  = alloc((size_t)N*64);
  float*  tbuf  = alloc((size_t)N*64);    // h1, later update-MLP hidden
  float*  neigh = alloc((size_t)N*64);
  float*  Ubuf  = alloc((size_t)N*32);
  float*  rho   = alloc((size_t)N);
  float*  loglib= alloc((size_t)N);
  float*  WT    = alloc((size_t)K*C);
  float*  bcorr = alloc((size_t)S*C);
  float4* csr4  = (float4*)alloc((size_t)E*4);
  int*    cnt   = (int*)alloc((size_t)N);
  int*    offs  = (int*)alloc((size_t)N + 64);
  int*    fillc = (int*)alloc((size_t)N);
  int*    blksum= (int*)alloc(256);

  hipMemsetAsync(cnt,   0, sizeof(int)*(size_t)N, stream);
  hipMemsetAsync(fillc, 0, sizeof(int)*(size_t)N, stream);

  // prep
  k_prep_node<<<(N+255)/256,256,0,stream>>>(rho_raw, lib, rho, loglib, N);
  k_prep_W<<<(K*C+255)/256,256,0,stream>>>(W_raw, WT, C, K);
  k_prep_bcorr<<<1,256,0,stream>>>(P, Q, bcorr, S, R, C);

  // CSR by dst
  k_hist<<<(E+255)/256,256,0,stream>>>(dst, cnt, E);
  int nblk = (N+1023)/1024;
  k_scan1<<<nblk,1024,0,stream>>>(cnt, offs, blksum, N);
  k_scan2<<<1,64,0,stream>>>(blksum, nblk);
  k_scan3<<<(N+256)/256,256,0,stream>>>(offs, blksum, N, E);
  k_fill<<<(E+255)/256,256,0,stream>>>(src, dst, base_w, dist, rho, offs, fillc, csr4, E);

  // encoder
  k_enc1<<<(N+127)/128,256,0,stream>>>(x_common, enc_w1, enc_b1, tbuf, N, C);
  int gsm = (N+63)/64;
  // h = relu(h1@enc_w2 + b2) -> pkA.h
  k_small_gemm<64,1><<<gsm,256,0,stream>>>(tbuf,64,0, enc_w2, enc_b2, pkA,128,64,
                                           nullptr,0,0, nullptr,nullptr, N);
  // gate projections: a = h@gw1[0:64], b = h@gw1[64:128]
  k_small_gemm<64,0><<<gsm,256,0,stream>>>(pkA,128,64, gate_w1, nullptr, pkA,128,0,
                                           nullptr,0,0, nullptr,nullptr, N);
  k_small_gemm<64,0><<<gsm,256,0,stream>>>(pkA,128,64, gate_w1+64*64, nullptr, bbuf,64,0,
                                           nullptr,0,0, nullptr,nullptr, N);

  float* cur = pkA; float* nxt = pkB;
  for (int l = 0; l < L; ++l){
    k_agg<<<(N+3)/4,256,0,stream>>>(cur, bbuf, rho, csr4, offs,
                                    gate_w1, gate_b1, gate_w2, gate_b2, neigh, N);
    k_small_gemm<64,1><<<gsm,256,0,stream>>>(neigh,64,0, upd_w1 + (size_t)l*64*64, upd_b1 + l*64,
                                             tbuf,64,0, nullptr,0,0, nullptr,nullptr, N);
    k_small_gemm<64,2><<<gsm,256,0,stream>>>(tbuf,64,0, upd_w2 + (size_t)l*64*64, upd_b2 + l*64,
                                             nxt,128,64, cur,128,64, ln_g + l*64, ln_b + l*64, N);
    if (l + 1 < L){
      k_small_gemm<64,0><<<gsm,256,0,stream>>>(nxt,128,64, gate_w1, nullptr, nxt,128,0,
                                               nullptr,0,0, nullptr,nullptr, N);
      k_small_gemm<64,0><<<gsm,256,0,stream>>>(nxt,128,64, gate_w1+64*64, nullptr, bbuf,64,0,
                                               nullptr,0,0, nullptr,nullptr, N);
    }
    float* t = cur; cur = nxt; nxt = t;
  }

  // U = softplus(h @ toU_w + toU_b)
  k_small_gemm<32,3><<<gsm,256,0,stream>>>(cur,128,64, toU_w, toU_b, Ubuf,32,0,
                                           nullptr,0,0, nullptr,nullptr, N);

  // mu
  dim3 fg((C+255)/256, (N+63)/64);
  k_final<<<fg,256,0,stream>>>(Ubuf, WT, alpha, bcorr, loglib, sid, (float*)d_out, N, C, 64);
}